// Round 12
// baseline (280.086 us; speedup 1.0000x reference)
//
#include <hip/hip_runtime.h>
#include <math.h>

// Problem constants
#define B_DIM 8
#define T_DIM 2048
#define C_DIM 1024
#define HS_DIM 128
#define VD 256
#define M_DIM (B_DIM * T_DIM)            // 16384 rows
#define QK_ELEMS (M_DIM * HS_DIM)        // 2,097,152 elems per (q|k) term
#define SCALE 0.088388347648318447f      // 1/sqrt(128)
#define LOG_THETA 9.210340371976184f     // ln(10000)

// workspace layout (ushort units)
#define QB_OFF   0u
#define KB_OFF   4194304u
#define VT_OFF   8388608u
#define WT_OFF   12582912u
#define XBH_OFF  13369344u               // x-bf16 rows 8192..16383
#define LAM_OFF  21757952u
#define BAR_OFF  21757960u               // 2 x u32 barrier counters
#define XSPLIT_ELEMS 8388608u            // rows 0..8191 of x-bf16 live in d_out

typedef short s8v   __attribute__((ext_vector_type(8)));   // 8 bf16 (4 VGPRs)
typedef float f32x4 __attribute__((ext_vector_type(4)));
typedef float f32x16 __attribute__((ext_vector_type(16)));

// attn LDS geometry (also the kernel's total static LDS)
#define PSTR 72      // P LDS row stride: 64 keys + 8 pad
#define OSTR 260     // O combine stride (fp32 words)
#define BUFB 65536   // bytes per K+V buffer
#define P_OFF 131072
#define PSZ  9216    // per-strip P region
#define SM_TOTAL 149504

// ---------- helpers ----------
__device__ __forceinline__ unsigned int bf16_rne(float f) {
    unsigned int u = __float_as_uint(f);
    return (u + 0x7fffu + ((u >> 16) & 1u)) >> 16;
}
__device__ __forceinline__ unsigned int pack_bf2(float lo, float hi) {
    return bf16_rne(lo) | (bf16_rne(hi) << 16);
}
__device__ __forceinline__ void async_cp16(const unsigned short* g, unsigned short* l) {
    __builtin_amdgcn_global_load_lds(
        (const __attribute__((address_space(1))) unsigned int*)g,
        (__attribute__((address_space(3))) unsigned int*)l, 16, 0, 0);
}
// Device-wide barrier: all 256 blocks are resident (grid == CU count, 1
// block/CU by LDS), so spin is deadlock-free. Release flushes the XCD L2;
// acquire invalidates, giving cross-XCD visibility of prior phase's stores.
__device__ __forceinline__ void grid_barrier(unsigned int* ctr) {
    __syncthreads();
    if (threadIdx.x == 0) {
        __atomic_fetch_add(ctr, 1u, __ATOMIC_ACQ_REL);
        while (__atomic_load_n(ctr, __ATOMIC_ACQUIRE) < 256u)
            __builtin_amdgcn_s_sleep(16);
    }
    __syncthreads();
}

// ---------- the whole op in one kernel: prep | gemm | attn ----------
__global__ __launch_bounds__(512, 1) void mega_kernel(
    const float* __restrict__ x,
    const float* __restrict__ Wq, const float* __restrict__ Wk,
    const float* __restrict__ Wv,
    const float* __restrict__ lq, const float* __restrict__ lk,
    const int* __restrict__ lidx,
    unsigned short* __restrict__ xlo, unsigned short* __restrict__ xhi,
    unsigned short* __restrict__ wt, float* __restrict__ lamb,
    unsigned short* __restrict__ qb, unsigned short* __restrict__ kb,
    unsigned short* __restrict__ vT, float* __restrict__ outp,
    unsigned int* __restrict__ bar) {
    __shared__ __align__(16) unsigned char smem[SM_TOTAL];

    const int t = threadIdx.x;
    const int bid = blockIdx.x;            // 256 blocks == 256 CUs

    // ================= P1: prep (cast_x grid-strided, cast_wt x3, lam) ====
    {
        const int idx = bid * 512 + t;     // 0..131071
        #pragma unroll 4
        for (int iter = 0; iter < 16; ++iter) {
            const size_t i8 = (size_t)(idx + (iter << 17)) * 8;
            float4 a = *(const float4*)(x + i8);
            float4 b = *(const float4*)(x + i8 + 4);
            uint4 u;
            u.x = pack_bf2(a.x, a.y); u.y = pack_bf2(a.z, a.w);
            u.z = pack_bf2(b.x, b.y); u.w = pack_bf2(b.z, b.w);
            unsigned short* dst = (i8 < XSPLIT_ELEMS) ? (xlo + i8)
                                                      : (xhi + (i8 - XSPLIT_ELEMS));
            *(uint4*)dst = u;
        }
    }
    {
        // cast_wt: Q/K cols RoPE-permuted pi(n)=2*((n&15)+((n>>5)<<4))+((n>>4)&1)
        float (*tile)[33] = (float(*)[33])smem;
        for (int r = 0; r < 3; ++r) {
            const int bxx = bid + (r << 8); // 0..767
            const int n0 = (bxx % 24) * 32;
            const int k0 = (bxx / 24) * 32;
            const int seg = n0 >> 7;
            const int nl = t & 31;
            const int ng = n0 + nl;
            const int ngl = ng & 127;
            const int pcol = 2 * ((ngl & 15) + ((ngl >> 5) << 4)) + ((ngl >> 4) & 1);
            const float* src; int ld;
            if (seg < 2)      { src = Wq + (size_t)seg * (C_DIM * HS_DIM) + pcol; ld = 128; }
            else if (seg < 4) { src = Wk + (size_t)(seg - 2) * (C_DIM * HS_DIM) + pcol; ld = 128; }
            else              { src = Wv + (ng - 512); ld = 256; }
            #pragma unroll
            for (int rep = 0; rep < 2; ++rep) {
                int kl = (t >> 5) + rep * 16;
                tile[kl][nl] = src[(size_t)(k0 + kl) * ld];
            }
            __syncthreads();
            unsigned int* wt32 = (unsigned int*)wt;
            {
                int nl2 = t >> 4;          // 0..31
                int k2 = (t & 15) * 2;
                unsigned int u = pack_bf2(tile[k2][nl2], tile[k2 + 1][nl2]);
                wt32[((size_t)(n0 + nl2) * 1024 + k0 + k2) >> 1] = u;
            }
            __syncthreads();               // tile reused next r
        }
    }
    if (bid == 0 && t < 64) {
        float s0 = expf(lq[t] * lk[t]) + expf(lq[t + 64] * lk[t + 64]);
        float s1 = expf(lq[128 + t] * lk[128 + t]) + expf(lq[192 + t] * lk[192 + t]);
        #pragma unroll
        for (int off = 32; off > 0; off >>= 1) {
            s0 += __shfl_down(s0, off);
            s1 += __shfl_down(s1, off);
        }
        if (t == 0) {
            float e0 = s0 * (1.0f / 128.0f);
            float e1 = s1 * (1.0f / 128.0f);
            float li = 0.8f - 0.6f * expf(-0.3f * ((float)lidx[0] - 1.0f));
            lamb[0] = e0 + li;             // +lam0
            lamb[1] = -(e1 - e0 + li);     // -lam1
        }
    }
    grid_barrier(bar + 0);

    // ================= P2: gemm (two 256-thread halves, R11 pipeline) =====
    {
        const int half = t >> 8, th = t & 255;
        const int wv = th >> 6, lane = th & 63;
        const int quad = lane >> 4, l15 = lane & 15;
        const int wr = wv >> 1, wc = wv & 1;
        unsigned short* AB = (unsigned short*)(smem + half * 65536); // [2buf][2][8192]

        int srow[4], sco[4];
        #pragma unroll
        for (int rep = 0; rep < 4; ++rep) {
            const int ci = th + rep * 256;
            srow[rep] = ci >> 3;
            sco[rep] = ((ci & 7) ^ (srow[rep] & 7)) * 8;
        }

        #pragma unroll 1
        for (int r = 0; r < 2; ++r) {
            const int tile = bid * 2 + half + (r << 9);   // 0..1023
            const bool active = tile < 768;
            const int m0 = (tile & 127) * 128;
            const int n0 = (tile >> 7) * 128;
            const unsigned short* xbase = (m0 < 8192)
                ? (xlo + (size_t)m0 * C_DIM) : (xhi + (size_t)(m0 - 8192) * C_DIM);
            const unsigned short* wbase = wt + (size_t)n0 * C_DIM;

            f32x4 acc[4][4];
            #pragma unroll
            for (int i = 0; i < 4; ++i)
                #pragma unroll
                for (int j = 0; j < 4; ++j) acc[i][j] = (f32x4){0.f, 0.f, 0.f, 0.f};

            if (active) {
                #pragma unroll
                for (int rep = 0; rep < 4; ++rep) {
                    const int ci = th + rep * 256;
                    async_cp16(xbase + (size_t)srow[rep] * C_DIM + sco[rep], AB + ci * 8);
                    async_cp16(wbase + (size_t)srow[rep] * C_DIM + sco[rep], AB + 8192 + ci * 8);
                }
            }
            for (int it = 0; it < 16; ++it) {
                const int cur = it & 1;
                asm volatile("s_waitcnt vmcnt(0)" ::: "memory");
                __builtin_amdgcn_s_barrier();
                if (active && it + 1 < 16) {
                    const int kn = (it + 1) * 64;
                    const int nb = (cur ^ 1) * 2;
                    #pragma unroll
                    for (int rep = 0; rep < 4; ++rep) {
                        const int ci = th + rep * 256;
                        async_cp16(xbase + (size_t)srow[rep] * C_DIM + kn + sco[rep],
                                   AB + nb * 8192 + ci * 8);
                        async_cp16(wbase + (size_t)srow[rep] * C_DIM + kn + sco[rep],
                                   AB + (nb + 1) * 8192 + ci * 8);
                    }
                }
                if (active) {
                    const unsigned short* As = AB + cur * 16384;
                    const unsigned short* Bs = AB + cur * 16384 + 8192;
                    #pragma unroll
                    for (int kk = 0; kk < 2; ++kk) {
                        s8v af[4], bf[4];
                        #pragma unroll
                        for (int i = 0; i < 4; ++i) {
                            const int row = wr * 64 + i * 16 + l15;
                            const int xch = (kk * 4 + quad) ^ (row & 7);
                            af[i] = *(const s8v*)&As[row * 64 + xch * 8];
                        }
                        #pragma unroll
                        for (int j = 0; j < 4; ++j) {
                            const int row = wc * 64 + j * 16 + l15;
                            const int xch = (kk * 4 + quad) ^ (row & 7);
                            bf[j] = *(const s8v*)&Bs[row * 64 + xch * 8];
                        }
                        #pragma unroll
                        for (int i = 0; i < 4; ++i)
                            #pragma unroll
                            for (int j = 0; j < 4; ++j)
                                acc[i][j] = __builtin_amdgcn_mfma_f32_16x16x32_bf16(
                                    af[i], bf[j], acc[i][j], 0, 0, 0);
                    }
                }
            }
            if (active) {
                const int seg = n0 >> 7;   // 0..5
                if (seg < 4) {
                    unsigned short* dstbuf = ((seg < 2) ? qb : kb)
                        + (size_t)(seg & 1) * QK_ELEMS;
                    const int mi0 = l15 + 32 * wc;
                    const int mi1 = mi0 + 16;
                    const float freq0 = __expf((float)mi0 * (-LOG_THETA / 64.f));
                    const float freq1 = __expf((float)mi1 * (-LOG_THETA / 64.f));
                    #pragma unroll
                    for (int i = 0; i < 4; ++i) {
                        #pragma unroll
                        for (int e = 0; e < 4; ++e) {
                            const int m = m0 + wr * 64 + i * 16 + quad * 4 + e;
                            const float trow = (float)(m & (T_DIM - 1));
                            unsigned int* p32 = (unsigned int*)(dstbuf + (size_t)m * HS_DIM);
                            float sn0, cs0, sn1, cs1;
                            __sincosf(trow * freq0, &sn0, &cs0);
                            __sincosf(trow * freq1, &sn1, &cs1);
                            const float xr0 = acc[i][0][e], xi0 = acc[i][1][e];
                            const float xr1 = acc[i][2][e], xi1 = acc[i][3][e];
                            p32[mi0] = pack_bf2(xr0 * cs0 - xi0 * sn0, xr0 * sn0 + xi0 * cs0);
                            p32[mi1] = pack_bf2(xr1 * cs1 - xi1 * sn1, xr1 * sn1 + xi1 * cs1);
                        }
                    }
                } else {
                    const int bq = m0 >> 11;
                    const int tbase = m0 & (T_DIM - 1);
                    unsigned int* vT32 = (unsigned int*)vT;
                    #pragma unroll
                    for (int j = 0; j < 4; ++j) {
                        const int d = (seg - 4) * 128 + wc * 64 + j * 16 + l15;
                        const size_t rowbase = (size_t)(bq * VD + d) * (T_DIM / 2);
                        #pragma unroll
                        for (int i = 0; i < 4; ++i) {
                            const int tok = tbase + wr * 64 + i * 16 + quad * 4;
                            uint2 u;
                            u.x = pack_bf2(acc[i][j][0], acc[i][j][1]);
                            u.y = pack_bf2(acc[i][j][2], acc[i][j][3]);
                            *(uint2*)&vT32[rowbase + (tok >> 1)] = u;
                        }
                    }
                }
            }
            __syncthreads();               // AB reused by next r
        }
    }
    grid_barrier(bar + 1);

    // ================= P3: attn (R9/R11 structure verbatim) ===============
    {
        const int id = bid;
        const int b = id & 7;              // batch -> XCD round-robin
        const int kp = id >> 3;            // 0..31 pair index

        const int w = t >> 6, lane = t & 63;
        const int l31 = lane & 31, lh = lane >> 5;
        const int sg = w >> 2;             // strip slot: 0=heavy, 1=light
        const int term = w & 1;
        const int kh = (w >> 1) & 1;       // QK k-half / PV d-half

        const int strip = sg ? kp : (63 - kp);
        const int q0 = strip * 32;
        const int ntS = (strip >> 1) + 1;  // this strip's 64-key tiles
        const int ntB = ((63 - kp) >> 1) + 1;  // block tiles (heavy strip)

        unsigned short* Ps = (unsigned short*)(smem + P_OFF + sg * PSZ);
        float* Lsum = (float*)(smem + P_OFF + sg * PSZ);
        float* Ol = (float*)(smem + sg * BUFB);

        const float cn = lamb[term];       // lam[1] carries the minus sign

        const unsigned short* qrow = qb
            + ((size_t)(term * B_DIM + b) * T_DIM + q0 + l31) * HS_DIM + lh * 8;
        s8v qa[8];
        #pragma unroll
        for (int ks = 0; ks < 8; ++ks)
            qa[ks] = *(const s8v*)(qrow + ks * 16);

        unsigned int kOffA[4], vOffA[4];
        #pragma unroll
        for (int rep = 0; rep < 4; ++rep) {
            const int c = t + rep * 512;
            const int rowg = c >> 4, slot = c & 15;
            const int kterm = rowg >> 6, krw = rowg & 63;
            const int kss = slot ^ (krw & 15);
            kOffA[rep] = (unsigned int)(((kterm * B_DIM + b) * T_DIM + krw) * HS_DIM
                                        + kss * 8);
            const int drow = rowg;
            const int vss = slot ^ (drow & 15);
            const int dim = 2 * drow + (vss >> 3), tokc = vss & 7;
            vOffA[rep] = (unsigned int)((b * VD + dim) * T_DIM + tokc * 8);
        }

        f32x16 o[4];
        #pragma unroll
        for (int dt = 0; dt < 4; ++dt)
            #pragma unroll
            for (int r = 0; r < 16; ++r) o[dt][r] = 0.f;
        float l_acc[16];
        #pragma unroll
        for (int r = 0; r < 16; ++r) l_acc[r] = 0.f;

        {
            unsigned short* kb0 = (unsigned short*)(smem + w * 1024);
            unsigned short* vb0 = (unsigned short*)(smem + 32768 + w * 1024);
            #pragma unroll
            for (int rep = 0; rep < 4; ++rep) {
                async_cp16(kb + kOffA[rep], kb0 + rep * 4096);
                async_cp16(vT + vOffA[rep], vb0 + rep * 4096);
            }
        }
        __syncthreads();

        const int krow = kh * 32 + l31;
        const int k15 = l31 & 15;

        for (int it = 0; it < ntB; ++it) {
            const int s0 = it * 64;
            const unsigned char* buf = smem + (it & 1) * BUFB;

            if (it + 1 < ntB) {
                const int sn = s0 + 64;
                unsigned char* nbuf = smem + ((it + 1) & 1) * BUFB;
                unsigned short* kbn = (unsigned short*)(nbuf + w * 1024);
                unsigned short* vbn = (unsigned short*)(nbuf + 32768 + w * 1024);
                #pragma unroll
                for (int rep = 0; rep < 4; ++rep) {
                    async_cp16(kb + kOffA[rep] + (size_t)sn * HS_DIM, kbn + rep * 4096);
                    async_cp16(vT + vOffA[rep] + sn, vbn + rep * 4096);
                }
            }

            if (it < ntS) {
                const unsigned short* Kb = (const unsigned short*)buf;
                f32x16 sc;
                #pragma unroll
                for (int r = 0; r < 16; ++r) sc[r] = 0.f;
                __builtin_amdgcn_s_setprio(1);
                #pragma unroll
                for (int ks = 0; ks < 8; ++ks) {
                    const int xx = (ks * 2 + lh) ^ k15;
                    s8v kf = *(const s8v*)&Kb[(term * 64 + krow) * 128 + xx * 8];
                    sc = __builtin_amdgcn_mfma_f32_32x32x16_bf16(qa[ks], kf, sc, 0, 0, 0);
                }
                __builtin_amdgcn_s_setprio(0);
                const int key = s0 + kh * 32 + l31;
                #pragma unroll
                for (int r = 0; r < 16; ++r) {
                    const int row = (r & 3) + 8 * (r >> 2) + 4 * lh;
                    const float p = (key <= q0 + row) ? __expf(sc[r] * SCALE) : 0.f;
                    l_acc[r] += p;
                    Ps[(term * 32 + row) * PSTR + kh * 32 + l31] = (unsigned short)bf16_rne(p);
                }
            }
            asm volatile("s_waitcnt lgkmcnt(0)\n\ts_barrier" ::: "memory");
            __builtin_amdgcn_sched_barrier(0);

            if (it < ntS) {
                const unsigned short* Vb = (const unsigned short*)(buf + 32768);
                __builtin_amdgcn_s_setprio(1);
                #pragma unroll
                for (int ks = 0; ks < 4; ++ks) {
                    s8v pa = *(const s8v*)&Ps[(term * 32 + l31) * PSTR + ks * 16 + lh * 8];
                    #pragma unroll
                    for (int dt = 0; dt < 4; ++dt) {
                        const int dim = kh * 128 + dt * 32 + l31;
                        const int drow = dim >> 1;
                        const int xx = ((dim & 1) * 8 + ks * 2 + lh) ^ (drow & 15);
                        s8v vb = *(const s8v*)&Vb[(drow * 16 + xx) * 8];
                        o[dt] = __builtin_amdgcn_mfma_f32_32x32x16_bf16(pa, vb, o[dt], 0, 0, 0);
                    }
                }
                __builtin_amdgcn_s_setprio(0);
            }
            __syncthreads();
        }

        #pragma unroll
        for (int r = 0; r < 16; ++r) {
            float lt = l_acc[r];
            #pragma unroll
            for (int off = 1; off < 32; off <<= 1) lt += __shfl_xor(lt, off);
            if (l31 == 0) {
                const int row = (r & 3) + 8 * (r >> 2) + 4 * lh;
                Lsum[(term * 2 + kh) * 32 + row] = lt;
            }
        }
        __syncthreads();
        float inv[16];
        #pragma unroll
        for (int r = 0; r < 16; ++r) {
            const int row = (r & 3) + 8 * (r >> 2) + 4 * lh;
            inv[r] = cn / (Lsum[(term * 2 + 0) * 32 + row] + Lsum[(term * 2 + 1) * 32 + row]);
        }

        if (term) {
            #pragma unroll
            for (int dt = 0; dt < 4; ++dt)
                #pragma unroll
                for (int r = 0; r < 16; ++r) {
                    const int row = (r & 3) + 8 * (r >> 2) + 4 * lh;
                    Ol[row * OSTR + kh * 128 + dt * 32 + l31] = o[dt][r] * inv[r];
                }
        }
        __syncthreads();
        if (!term) {
            #pragma unroll
            for (int dt = 0; dt < 4; ++dt)
                #pragma unroll
                for (int r = 0; r < 16; ++r) {
                    const int row = (r & 3) + 8 * (r >> 2) + 4 * lh;
                    Ol[row * OSTR + kh * 128 + dt * 32 + l31] += o[dt][r] * inv[r];
                }
        }
        __syncthreads();
        #pragma unroll
        for (int rep = 0; rep < 8; ++rep) {
            int idx = (t & 255) + rep * 256;   // 32 rows x 64 float4
            int row = idx >> 6, c4 = idx & 63;
            float4 val = *(const float4*)&Ol[row * OSTR + c4 * 4];
            *(float4*)&outp[((size_t)(b * T_DIM + q0 + row)) * VD + c4 * 4] = val;
        }
    }
}

extern "C" void kernel_launch(void* const* d_in, const int* in_sizes, int n_in,
                              void* d_out, int out_size, void* d_ws, size_t ws_size,
                              hipStream_t stream) {
    const float* x  = (const float*)d_in[0];
    const float* Wq = (const float*)d_in[1];
    const float* Wk = (const float*)d_in[2];
    const float* Wv = (const float*)d_in[3];
    const float* lq = (const float*)d_in[4];
    const float* lk = (const float*)d_in[5];
    const int* lidx = (const int*)d_in[6];

    unsigned short* ws = (unsigned short*)d_ws;
    unsigned short* qb   = ws + QB_OFF;    // [2][8][2048][128] bf16
    unsigned short* kb   = ws + KB_OFF;    // [2][8][2048][128] bf16
    unsigned short* vTb  = ws + VT_OFF;    // [8][256][2048] bf16
    unsigned short* wtb  = ws + WT_OFF;    // [768][1024] bf16
    unsigned short* xbhi = ws + XBH_OFF;   // x-bf16 rows 8192..16383
    float* lamb = (float*)(ws + LAM_OFF);
    unsigned int* barb = (unsigned int*)(ws + BAR_OFF);
    unsigned short* xblo = (unsigned short*)d_out;  // scratch; attn overwrites d_out
    (void)ws_size; (void)in_sizes; (void)n_in; (void)out_size;

    hipMemsetAsync(barb, 0, 8, stream);
    mega_kernel<<<dim3(256), dim3(512), 0, stream>>>(
        x, Wq, Wk, Wv, lq, lk, lidx, xblo, xbhi, wtb, lamb,
        qb, kb, vTb, (float*)d_out, barb);
}